// Round 12
// baseline (2234.656 us; speedup 1.0000x reference)
//
#include <hip/hip_runtime.h>
#include <hip/hip_bf16.h>
#include <math.h>

static constexpr int NLAT = 128, NLON = 256, MM = 128;
static constexpr int EMB = 256, INCH = 36, OUTCH = 6, HID = 512, NLAYERS = 4;
static constexpr int YN = 32768;
static constexpr long RB = 4194304;   // per-reim block, elements

using bf16x8 = __attribute__((ext_vector_type(8))) __bf16;
using f32x4  = __attribute__((ext_vector_type(4))) float;

static constexpr int BM = 128, BN = 128, BK = 32, LDP = 40;

__device__ __forceinline__ void cvt_hl(float v, __bf16& h, __bf16& l)
{
    h = (__bf16)v;
    l = (__bf16)(v - (float)h);
}

// ============== split-bf16 NT GEMM, bf16-fed ==============
// C = alpha * A·B^T (+addf) (+addh+addl) (+bias[col]) (relu); outputs f32 and/or hi/lo bf16.
__global__ __launch_bounds__(256)
void gemm_hl(const __bf16* __restrict__ Agh, const __bf16* __restrict__ Agl,
             const __bf16* __restrict__ Bgh, const __bf16* __restrict__ Bgl,
             int M, int N, int K, int lda, int ldb, int ldc,
             long sAz, long sBz, unsigned zmaskB, long sCz,
             float* __restrict__ Cf, __bf16* __restrict__ Chi, __bf16* __restrict__ Clo,
             const float* __restrict__ addf,
             const __bf16* __restrict__ addh, const __bf16* __restrict__ addl,
             const float* __restrict__ bias,
             int kfromz, float alpha, int relu)
{
    __shared__ __bf16 Ah[BM][LDP], Al[BM][LDP], Bh[BN][LDP], Bl[BN][LDP];

    const int z = blockIdx.z;
    const long aOff = (long)z * sAz, bOff = (long)(z & zmaskB) * sBz, cOff = (long)z * sCz;
    const int m0 = blockIdx.y * BM, n0 = blockIdx.x * BN;
    const int tid = threadIdx.x, lane = tid & 63, wave = tid >> 6;
    const int wr = wave >> 1, wc = wave & 1;
    const int fr = lane & 15, fkb = lane >> 4;
    const int sr = tid >> 1, sh = (tid & 1) << 4;

    int kst = 0;
    if (kfromz) kst = ((z & 127) >> 5) << 5;

    f32x4 acc[4][4];
    #pragma unroll
    for (int i = 0; i < 4; ++i)
        #pragma unroll
        for (int j = 0; j < 4; ++j) acc[i][j] = (f32x4)0.f;

    const int ga = m0 + sr, gb = n0 + sr;
    const __bf16* Arh = Agh + aOff + (long)ga * lda + sh;
    const __bf16* Arl = Agl + aOff + (long)ga * lda + sh;
    const __bf16* Brh = Bgh + bOff + (long)gb * ldb + sh;
    const __bf16* Brl = Bgl + bOff + (long)gb * ldb + sh;

    bf16x8 pAh0, pAh1, pAl0, pAl1, pBh0, pBh1, pBl0, pBl1;

    auto loadA = [&](int k0) {
        if (ga < M && (k0 + sh + 16) <= K) {
            pAh0 = *(const bf16x8*)(Arh + k0); pAh1 = *(const bf16x8*)(Arh + k0 + 8);
            pAl0 = *(const bf16x8*)(Arl + k0); pAl1 = *(const bf16x8*)(Arl + k0 + 8);
        } else {
            #pragma unroll
            for (int e = 0; e < 8; ++e) {
                const bool ok0 = (ga < M) && (k0 + sh + e) < K;
                const bool ok1 = (ga < M) && (k0 + sh + 8 + e) < K;
                pAh0[e] = ok0 ? Arh[k0 + e] : (__bf16)0.f;
                pAl0[e] = ok0 ? Arl[k0 + e] : (__bf16)0.f;
                pAh1[e] = ok1 ? Arh[k0 + 8 + e] : (__bf16)0.f;
                pAl1[e] = ok1 ? Arl[k0 + 8 + e] : (__bf16)0.f;
            }
        }
    };
    auto loadB = [&](int k0) {
        if (gb < N && (k0 + sh + 16) <= K) {
            pBh0 = *(const bf16x8*)(Brh + k0); pBh1 = *(const bf16x8*)(Brh + k0 + 8);
            pBl0 = *(const bf16x8*)(Brl + k0); pBl1 = *(const bf16x8*)(Brl + k0 + 8);
        } else {
            #pragma unroll
            for (int e = 0; e < 8; ++e) {
                const bool ok0 = (gb < N) && (k0 + sh + e) < K;
                const bool ok1 = (gb < N) && (k0 + sh + 8 + e) < K;
                pBh0[e] = ok0 ? Brh[k0 + e] : (__bf16)0.f;
                pBl0[e] = ok0 ? Brl[k0 + e] : (__bf16)0.f;
                pBh1[e] = ok1 ? Brh[k0 + 8 + e] : (__bf16)0.f;
                pBl1[e] = ok1 ? Brl[k0 + 8 + e] : (__bf16)0.f;
            }
        }
    };

    loadA(kst); loadB(kst);

    for (int k0 = kst; k0 < K; k0 += BK) {
        *(bf16x8*)&Ah[sr][sh] = pAh0; *(bf16x8*)&Ah[sr][sh + 8] = pAh1;
        *(bf16x8*)&Al[sr][sh] = pAl0; *(bf16x8*)&Al[sr][sh + 8] = pAl1;
        *(bf16x8*)&Bh[sr][sh] = pBh0; *(bf16x8*)&Bh[sr][sh + 8] = pBh1;
        *(bf16x8*)&Bl[sr][sh] = pBl0; *(bf16x8*)&Bl[sr][sh + 8] = pBl1;
        __syncthreads();

        if (k0 + BK < K) { loadA(k0 + BK); loadB(k0 + BK); }

        bf16x8 fbh[4], fbl[4];
        #pragma unroll
        for (int j = 0; j < 4; ++j) {
            const int c = wc * 64 + j * 16 + fr;
            fbh[j] = *(const bf16x8*)&Bh[c][fkb * 8];
            fbl[j] = *(const bf16x8*)&Bl[c][fkb * 8];
        }
        #pragma unroll
        for (int i = 0; i < 4; ++i) {
            const int r = wr * 64 + i * 16 + fr;
            const bf16x8 fah = *(const bf16x8*)&Ah[r][fkb * 8];
            const bf16x8 fal = *(const bf16x8*)&Al[r][fkb * 8];
            #pragma unroll
            for (int j = 0; j < 4; ++j) {
                acc[i][j] = __builtin_amdgcn_mfma_f32_16x16x32_bf16(fah, fbh[j], acc[i][j], 0, 0, 0);
                acc[i][j] = __builtin_amdgcn_mfma_f32_16x16x32_bf16(fah, fbl[j], acc[i][j], 0, 0, 0);
                acc[i][j] = __builtin_amdgcn_mfma_f32_16x16x32_bf16(fal, fbh[j], acc[i][j], 0, 0, 0);
            }
        }
        __syncthreads();
    }

    const int crow0 = (lane >> 4) * 4;
    #pragma unroll
    for (int i = 0; i < 4; ++i) {
        #pragma unroll
        for (int j = 0; j < 4; ++j) {
            #pragma unroll
            for (int r = 0; r < 4; ++r) {
                const int gm = m0 + wr * 64 + i * 16 + crow0 + r;
                const int gn = n0 + wc * 64 + j * 16 + fr;
                if (gm < M && gn < N) {
                    const long idx = cOff + (long)gm * ldc + gn;
                    float v = acc[i][j][r] * alpha;
                    if (addf) v += addf[idx];
                    if (addh) v += (float)addh[idx] + (float)addl[idx];
                    if (bias) v += bias[gn];
                    if (relu) v = fmaxf(v, 0.f);
                    if (Cf) Cf[idx] = v;
                    if (Chi) { __bf16 h, l; cvt_hl(v, h, l); Chi[idx] = h; Clo[idx] = l; }
                }
            }
        }
    }
}

// ============== transposes ==============
// hi/lo pair transpose: in[z][R][C] -> out[z][C][R]
__global__ __launch_bounds__(256)
void t2hl(const __bf16* __restrict__ ih, const __bf16* __restrict__ il,
          __bf16* __restrict__ oh, __bf16* __restrict__ ol,
          int R, int C, long siZ, long soZ)
{
    __shared__ __bf16 th[32][34], tl[32][34];
    const int z = blockIdx.z;
    const long iB = (long)z * siZ, oB = (long)z * soZ;
    const int c0 = blockIdx.x * 32, r0 = blockIdx.y * 32;
    const int tx = threadIdx.x & 31, tg = threadIdx.x >> 5;
    #pragma unroll
    for (int rr = tg; rr < 32; rr += 8) {
        const int r = r0 + rr, c = c0 + tx;
        const bool ok = (r < R && c < C);
        const long idx = iB + (long)r * C + c;
        th[rr][tx] = ok ? ih[idx] : (__bf16)0.f;
        tl[rr][tx] = ok ? il[idx] : (__bf16)0.f;
    }
    __syncthreads();
    #pragma unroll
    for (int cc = tg; cc < 32; cc += 8) {
        const int c = c0 + cc, r = r0 + tx;
        if (c < C && r < R) {
            const long idx = oB + (long)c * R + r;
            oh[idx] = th[tx][cc]; ol[idx] = tl[tx][cc];
        }
    }
}

// hi/lo rot: in[bat][a][b][c] -> out[bat][c][b][a]
__global__ __launch_bounds__(256)
void rot3d_hl(const __bf16* __restrict__ ih, const __bf16* __restrict__ il,
              __bf16* __restrict__ oh, __bf16* __restrict__ ol,
              int Ad, int Bd, int Cd, long sIn, long sOut)
{
    __shared__ __bf16 th[32][34], tl[32][34];
    const int zz = blockIdx.z;
    const int b = zz % Bd, bat = zz / Bd;
    const long iB = (long)bat * sIn, oB = (long)bat * sOut;
    const int c0 = blockIdx.x * 32, a0 = blockIdx.y * 32;
    const int tx = threadIdx.x & 31, tg = threadIdx.x >> 5;
    #pragma unroll
    for (int aa = tg; aa < 32; aa += 8) {
        const int a = a0 + aa, c = c0 + tx;
        const bool ok = (a < Ad && c < Cd);
        const long idx = iB + ((long)a * Bd + b) * Cd + c;
        th[aa][tx] = ok ? ih[idx] : (__bf16)0.f;
        tl[aa][tx] = ok ? il[idx] : (__bf16)0.f;
    }
    __syncthreads();
    #pragma unroll
    for (int cc = tg; cc < 32; cc += 8) {
        const int c = c0 + cc, a = a0 + tx;
        if (c < Cd && a < Ad) {
            const long idx = oB + ((long)c * Bd + b) * Ad + a;
            oh[idx] = th[tx][cc]; ol[idx] = tl[tx][cc];
        }
    }
}

// f32 in [R][C] -> transposed hi/lo out [C][Rd] (zero-pad rows R..Rd)
__global__ __launch_bounds__(256)
void t2cvtp(const float* __restrict__ in, __bf16* __restrict__ oh, __bf16* __restrict__ ol,
            int R, int C, int Rd)
{
    __shared__ float t[32][33];
    const int c0 = blockIdx.x * 32, r0 = blockIdx.y * 32;
    const int tx = threadIdx.x & 31, tg = threadIdx.x >> 5;
    #pragma unroll
    for (int rr = tg; rr < 32; rr += 8) {
        const int r = r0 + rr, c = c0 + tx;
        t[rr][tx] = (r < R && c < C) ? in[(long)r * C + c] : 0.f;
    }
    __syncthreads();
    #pragma unroll
    for (int cc = tg; cc < 32; cc += 8) {
        const int c = c0 + cc, r = r0 + tx;
        if (c < C && r < Rd) {
            __bf16 h, l; cvt_hl(t[tx][cc], h, l);
            oh[(long)c * Rd + r] = h; ol[(long)c * Rd + r] = l;
        }
    }
}

// plain f32 transpose (posT, final out)
__global__ __launch_bounds__(256)
void transpose2d(const float* __restrict__ in, float* __restrict__ out, int R, int C)
{
    __shared__ float t[32][33];
    const int c0 = blockIdx.x * 32, r0 = blockIdx.y * 32;
    const int tx = threadIdx.x & 31, tg = threadIdx.x >> 5;
    #pragma unroll
    for (int rr = tg; rr < 32; rr += 8) {
        const int r = r0 + rr, c = c0 + tx;
        t[rr][tx] = (r < R && c < C) ? in[(long)r * C + c] : 0.f;
    }
    __syncthreads();
    #pragma unroll
    for (int cc = tg; cc < 32; cc += 8) {
        const int c = c0 + cc, r = r0 + tx;
        if (c < C && r < R) out[(long)c * R + r] = t[tx][cc];
    }
}

// f32 weights [R][Ks] (row stride sld) -> hi/lo [R][Kd], zero-padded
__global__ __launch_bounds__(256)
void cvtp(const float* __restrict__ src, __bf16* __restrict__ oh, __bf16* __restrict__ ol,
          int R, int Ks, int Kd, int sld)
{
    const long i = (long)blockIdx.x * 256 + threadIdx.x;
    if (i >= (long)R * Kd) return;
    const int r = (int)(i / Kd), k = (int)(i % Kd);
    const float v = (k < Ks) ? src[(long)r * sld + k] : 0.f;
    __bf16 h, l; cvt_hl(v, h, l);
    oh[i] = h; ol[i] = l;
}

// ============== table builders (hi/lo direct) ==============
__global__ __launch_bounds__(256)
void make_dft_hl(__bf16* WfH, __bf16* WfL, __bf16* WiH, __bf16* WiL)
{
    const int i = blockIdx.x * 256 + threadIdx.x;
    const double w0 = 2.0 * 3.14159265358979323846 / 256.0;
    {
        const int n = i & 255, r = i >> 8, m = r & 127;
        const double th = (double)((m * n) & 255) * w0;
        const float v = (r < 128) ? (float)cos(th) : (float)-sin(th);
        __bf16 h, l; cvt_hl(v, h, l); WfH[i] = h; WfL[i] = l;
    }
    {
        const int k = i & 255, nn = i >> 8, m = k & 127;
        const double th = (double)((m * nn) & 255) * w0;
        const float sc = (m == 0 ? 1.0f : 2.0f) / 256.0f;
        const float v = (k < 128) ? sc * (float)cos(th) : -sc * (float)sin(th);
        __bf16 h, l; cvt_hl(v, h, l); WiH[i] = h; WiL[i] = l;
    }
}

__global__ __launch_bounds__(256)
void make_P1_hl(const float* __restrict__ pct, const float* __restrict__ wq,
                __bf16* __restrict__ PH, __bf16* __restrict__ PL)
{
    const long i = (long)blockIdx.x * 256 + threadIdx.x;
    const int y = (int)(i & 127);
    const int l = (int)((i >> 7) & 127);
    const int m = (int)(i >> 14);
    const float v = pct[((long)l * MM + m) * NLAT + y] * wq[y];
    __bf16 h, lo; cvt_hl(v, h, lo); PH[i] = h; PL[i] = lo;
}

__global__ __launch_bounds__(256)
void make_Q_hl(const float* __restrict__ pct, __bf16* __restrict__ QH, __bf16* __restrict__ QL)
{
    __shared__ float t[32][33];
    const int m = blockIdx.z;
    const int y0 = blockIdx.x * 32, l0 = blockIdx.y * 32;
    const int tx = threadIdx.x & 31, tg = threadIdx.x >> 5;
    #pragma unroll
    for (int ll = tg; ll < 32; ll += 8)
        t[ll][tx] = pct[((long)(l0 + ll) * MM + m) * NLAT + (y0 + tx)];
    __syncthreads();
    #pragma unroll
    for (int yy = tg; yy < 32; yy += 8) {
        const long idx = ((long)m * NLAT + (y0 + yy)) * MM + (l0 + tx);
        __bf16 h, l; cvt_hl(t[tx][yy], h, l);
        QH[idx] = h; QL[idx] = l;
    }
}

// ============== host ==============
struct HL { __bf16 *h, *l; };

extern "C" void kernel_launch(void* const* d_in, const int* in_sizes, int n_in,
                              void* d_out, int out_size, void* d_ws, size_t ws_size,
                              hipStream_t stream)
{
    const float* x       = (const float*)d_in[0];
    const float* pct     = (const float*)d_in[1];
    const float* wq      = (const float*)d_in[2];
    const float* pos     = (const float*)d_in[3];
    const float* enc_w   = (const float*)d_in[4];
    const float* spec_re = (const float*)d_in[5];
    const float* spec_im = (const float*)d_in[6];
    const float* skip_w  = (const float*)d_in[7];
    const float* skip_b  = (const float*)d_in[8];
    const float* mlp_w1  = (const float*)d_in[9];
    const float* mlp_b1  = (const float*)d_in[10];
    const float* mlp_w2  = (const float*)d_in[11];
    const float* mlp_b2  = (const float*)d_in[12];
    const float* dec_w1  = (const float*)d_in[13];
    const float* dec_b1  = (const float*)d_in[14];
    const float* dec_w2  = (const float*)d_in[15];

    char* base = (char*)d_ws;
    size_t off = 0;
    auto alloc = [&](size_t bytes) -> char* {
        char* p = base + off; off += (bytes + 255) & ~(size_t)255; return p;
    };
    auto allocHL = [&](long elems) -> HL {
        HL r; r.h = (__bf16*)alloc((size_t)elems * 2); r.l = (__bf16*)alloc((size_t)elems * 2); return r;
    };

    HL Wf  = allocHL(65536);
    HL Wi2 = allocHL(65536);
    HL P1  = allocHL(2097152);
    HL Q   = allocHL(2097152);
    HL enc = allocHL(256 * 48);
    HL skp = allocHL(4 * 65536);
    HL w1  = allocHL(4 * 131072);
    HL w2  = allocHL(4 * 131072);
    HL d1h = allocHL(512 * 256);
    HL d1x = allocHL(512 * 48);
    HL d2  = allocHL(6 * 512);
    HL xT  = allocHL((long)YN * 48);
    float* posT = (float*)alloc((size_t)8388608 * 4);
    HL hA  = allocHL(8388608);
    HL hB  = allocHL(8388608);
    HL S1  = allocHL(8388608);
    HL S2  = allocHL(8388608);
    HL mb  = allocHL(16777216);
    HL WtR = allocHL(8388608);
    HL WtI = allocHL(8388608);
    float* U = (float*)alloc((size_t)8388608 * 4);
    float* D = (float*)alloc((size_t)16777216 * 4);
    if (off > ws_size) return;

    // ---- tables & weight conversion ----
    make_dft_hl<<<256, 256, 0, stream>>>(Wf.h, Wf.l, Wi2.h, Wi2.l);
    make_P1_hl<<<8192, 256, 0, stream>>>(pct, wq, P1.h, P1.l);
    make_Q_hl<<<dim3(4, 4, 128), 256, 0, stream>>>(pct, Q.h, Q.l);
    cvtp<<<(256 * 48 + 255) / 256, 256, 0, stream>>>(enc_w, enc.h, enc.l, 256, 36, 48, 36);
    cvtp<<<(1024 * 256 + 255) / 256, 256, 0, stream>>>(skip_w, skp.h, skp.l, 1024, 256, 256, 256);
    cvtp<<<(2048 * 256 + 255) / 256, 256, 0, stream>>>(mlp_w1, w1.h, w1.l, 2048, 256, 256, 256);
    cvtp<<<(1024 * 512 + 255) / 256, 256, 0, stream>>>(mlp_w2, w2.h, w2.l, 1024, 512, 512, 512);
    cvtp<<<(512 * 256 + 255) / 256, 256, 0, stream>>>(dec_w1, d1h.h, d1h.l, 512, 256, 256, 292);
    cvtp<<<(512 * 48 + 255) / 256, 256, 0, stream>>>(dec_w1 + 256, d1x.h, d1x.l, 512, 36, 48, 292);
    cvtp<<<(6 * 512 + 255) / 256, 256, 0, stream>>>(dec_w2, d2.h, d2.l, 6, 512, 512, 512);
    t2cvtp<<<dim3(1024, 2), 256, 0, stream>>>(x, xT.h, xT.l, 36, YN, 48);
    transpose2d<<<dim3(1024, 8), 256, 0, stream>>>(pos, posT, 256, YN);

    auto g = [&](HL A, HL B, int M, int N, int K, int lda, int ldb, int ldc,
                 long sAz, long sBz, unsigned zm, long sCz, int Z,
                 float* Cf, HL Co, const float* addf, HL ad, const float* bias,
                 int kfz, float alpha, int relu, long Aoff = 0, long Boff = 0, long Coff = 0) {
        dim3 grid((N + BN - 1) / BN, (M + BM - 1) / BM, Z);
        gemm_hl<<<grid, 256, 0, stream>>>(
            A.h + Aoff, A.l + Aoff, B.h + Boff, B.l + Boff, M, N, K, lda, ldb, ldc,
            sAz, sBz, zm, sCz, Cf,
            Co.h ? Co.h + Coff : nullptr, Co.l ? Co.l + Coff : nullptr,
            addf, ad.h, ad.l, bias, kfz, alpha, relu);
    };
    const HL NIL = {nullptr, nullptr};

    // ---- encoder: hA[yn][c] = xT·enc^T + posT ----
    g(xT, enc, YN, EMB, 48, 48, 48, EMB, 0, 0, 0u, 0, 1,
      nullptr, hA, posT, NIL, nullptr, 0, 1.0f, 0);

    HL hcur = hA, hnext = hB;

    for (int l = 0; l < NLAYERS; ++l) {
        // T1: h[yn][c] -> hc[c][yn]
        t2hl<<<dim3(8, 1024, 1), 256, 0, stream>>>(hcur.h, hcur.l, S1.h, S1.l, YN, 256, 0, 0);
        // DFT: F[rm][(c,y)] = Wf·hc^T
        g(Wf, S1, 256, YN, 256, 256, 256, YN, 0, 0, 0u, 0, 1,
          nullptr, S2, nullptr, NIL, nullptr, 0, 1.0f, 0);
        // Legendre fwd (z=rm): A1[z][c][l] = F_z·P1_m^T
        g(S2, P1, 256, 128, 128, 128, 128, 128, 32768, 16384, 127u, 32768, 256,
          nullptr, S1, nullptr, NIL, nullptr, 0, 1.0f, 0);
        // t3 (per reim): [(m,c)][l] -> [l][(m,c)]
        t2hl<<<dim3(4, 1024, 2), 256, 0, stream>>>(S1.h, S1.l, S2.h, S2.l, 32768, 128, RB, RB);
        // spec weights -> [l][o][i] hi/lo
        t2cvtp<<<dim3(4, 2048), 256, 0, stream>>>(spec_re + (long)l * 8388608, WtR.h, WtR.l, 65536, 128, 65536);
        t2cvtp<<<dim3(4, 2048), 256, 0, stream>>>(spec_im + (long)l * 8388608, WtI.h, WtI.l, 65536, 128, 65536);
        // spec complex mult (z=l): Bspec = W·A
        g(WtR, S2, 256, 128, 256, 256, 256, 128, 65536, 32768, 0xFFFFFFFFu, 32768, 128,
          nullptr, S1, nullptr, NIL, nullptr, 0, 1.0f, 0);
        g(WtR, S2, 256, 128, 256, 256, 256, 128, 65536, 32768, 0xFFFFFFFFu, 32768, 128,
          nullptr, S1, nullptr, NIL, nullptr, 0, 1.0f, 0, 0, RB, RB);
        g(WtI, S2, 256, 128, 256, 256, 256, 128, 65536, 32768, 0xFFFFFFFFu, 32768, 128,
          nullptr, S1, nullptr, S1, nullptr, 0, -1.0f, 0, 0, RB, 0);
        g(WtI, S2, 256, 128, 256, 256, 256, 128, 65536, 32768, 0xFFFFFFFFu, 32768, 128,
          nullptr, {S1.h + RB, S1.l + RB}, nullptr, {S1.h + RB, S1.l + RB}, nullptr, 0, 1.0f, 0, 0, 0, 0);
        // rot: Bspec[r][l][o][m] -> Bt[r][m][o][l]
        rot3d_hl<<<dim3(4, 4, 512), 256, 0, stream>>>(S1.h, S1.l, S2.h, S2.l, 128, 256, 128, RB, RB);
        // Legendre inv (z=rm, K-start from m): G[z][c][y] = Bt_z·Q_m^T
        g(S2, Q, 256, 128, 128, 128, 128, 128, 32768, 16384, 127u, 32768, 256,
          nullptr, S1, nullptr, NIL, nullptr, 1, 1.0f, 0);
        // t7: G[rm][(c,y)] -> Gt[(c,y)][rm]
        t2hl<<<dim3(1024, 8, 1), 256, 0, stream>>>(S1.h, S1.l, S2.h, S2.l, 256, YN, 0, 0);
        // iDFT (z=y): u[y][w][c] = Wi2·Gt_y^T  (f32)
        g(Wi2, S2, 256, 256, 256, 256, 32768, 256, 0, 256, 0xFFFFFFFFu, 65536, 128,
          U, NIL, nullptr, NIL, nullptr, 0, 1.0f, 0);
        // skip: h2 = u + h·skip^T + b  -> S1 hi/lo
        g(hcur, skp, YN, EMB, 256, 256, 256, EMB, 0, 0, 0u, 0, 1,
          nullptr, S1, U, NIL, skip_b + (long)l * EMB, 0, 1.0f, 0, 0, (long)l * 65536, 0);
        // mlp1: m = relu(h2·W1^T + b1)
        g(S1, w1, YN, HID, 256, 256, 256, HID, 0, 0, 0u, 0, 1,
          nullptr, mb, nullptr, NIL, mlp_b1 + (long)l * HID, 0, 1.0f, 1, 0, (long)l * 131072, 0);
        // mlp2: h_next = m·W2^T + b2 + h
        g(mb, w2, YN, EMB, 512, 512, 512, EMB, 0, 0, 0u, 0, 1,
          nullptr, hnext, nullptr, hcur, mlp_b2 + (long)l * EMB, 0, 1.0f, 0, 0, (long)l * 131072, 0);
        HL t = hcur; hcur = hnext; hnext = t;
    }

    // ---- decoder ----
    g(hcur, d1h, YN, HID, 256, 256, 256, HID, 0, 0, 0u, 0, 1,
      D, NIL, nullptr, NIL, nullptr, 0, 1.0f, 0);
    g(xT, d1x, YN, HID, 48, 48, 48, HID, 0, 0, 0u, 0, 1,
      nullptr, mb, D, NIL, dec_b1, 0, 1.0f, 1);
    g(mb, d2, YN, OUTCH, 512, 512, 512, OUTCH, 0, 0, 0u, 0, 1,
      U, NIL, nullptr, NIL, nullptr, 0, 1.0f, 0);
    transpose2d<<<dim3(1, 1024), 256, 0, stream>>>(U, (float*)d_out, YN, OUTCH);

    (void)in_sizes; (void)n_in; (void)out_size;
}

// Round 13
// 2192.108 us; speedup vs baseline: 1.0194x; 1.0194x over previous
//
#include <hip/hip_runtime.h>
#include <hip/hip_bf16.h>
#include <math.h>

static constexpr int NLAT = 128, NLON = 256, MM = 128;
static constexpr int EMB = 256, OUTCH = 6, HID = 512, NLAYERS = 4;
static constexpr int YN = 32768;
static constexpr long RB = 4194304;

using bf16x8 = __attribute__((ext_vector_type(8))) __bf16;
using f32x4  = __attribute__((ext_vector_type(4))) float;

static constexpr int BM = 128, BN = 128, BK = 32;

__device__ __forceinline__ void cvt_hl(float v, __bf16& h, __bf16& l)
{
    h = (__bf16)v;
    l = (__bf16)(v - (float)h);
}

#define GLOAD16(g, l) __builtin_amdgcn_global_load_lds( \
    (const __attribute__((address_space(1))) void*)(g), \
    (__attribute__((address_space(3))) void*)(l), 16, 0, 0)

// ============== split-bf16 NT GEMM, gload_lds staging, swizzled LDS ==============
// C = alpha*A·B^T (+addf) (+addh+addl) (+bias[col]) (relu) -> f32 and/or hi/lo bf16.
__global__ __launch_bounds__(256)
void gemm_hl(const __bf16* __restrict__ Agh, const __bf16* __restrict__ Agl,
             const __bf16* __restrict__ Bgh, const __bf16* __restrict__ Bgl,
             int M, int N, int K, int lda, int ldb, int ldc,
             long sAz, long sBz, unsigned zmaskB, long sCz,
             float* __restrict__ Cf, __bf16* __restrict__ Chi, __bf16* __restrict__ Clo,
             const float* __restrict__ addf,
             const __bf16* __restrict__ addh, const __bf16* __restrict__ addl,
             const float* __restrict__ bias,
             int kfromz, float alpha, int relu)
{
    __shared__ __bf16 lds[4 * 128 * 32];   // Ah | Al | Bh | Bl, 8KB each, linear

    const int z = blockIdx.z;
    const long aOff = (long)z * sAz, bOff = (long)(z & zmaskB) * sBz, cOff = (long)z * sCz;
    const int m0 = blockIdx.y * BM, n0 = blockIdx.x * BN;
    const int tid = threadIdx.x, lane = tid & 63, wave = tid >> 6;
    const int wr = wave >> 1, wc = wave & 1;
    const int fr = lane & 15, fkb = lane >> 4;
    const int kst = kfromz ? (((z & 127) >> 5) << 5) : 0;

    // ---- staging role: wave w stages array w ----
    const __bf16* sbase;
    int sld, srow0;
    if      (wave == 0) { sbase = Agh + aOff; sld = lda; srow0 = m0; }
    else if (wave == 1) { sbase = Agl + aOff; sld = lda; srow0 = m0; }
    else if (wave == 2) { sbase = Bgh + bOff; sld = ldb; srow0 = n0; }
    else                { sbase = Bgl + bOff; sld = ldb; srow0 = n0; }
    const int krow = lane >> 2;                                // 0..15
    const int kcol = (((lane & 3) ^ ((krow >> 1) & 3)) << 3);  // swizzled k chunk (elements)
    __bf16* ldsw = lds + wave * 4096 + lane * 8;               // dest: uniform base + lane*16B

    auto stage = [&](int k0) {
        const __bf16* g = sbase + (long)(srow0 + krow) * sld + k0 + kcol;
        __bf16* l = ldsw;
        #pragma unroll
        for (int i = 0; i < 8; ++i) {
            GLOAD16(g, l);
            g += (long)16 * sld;
            l += 512;
        }
    };

    f32x4 acc[4][4];
    #pragma unroll
    for (int i = 0; i < 4; ++i)
        #pragma unroll
        for (int j = 0; j < 4; ++j) acc[i][j] = (f32x4)0.f;

    const int swzf = ((fr >> 1) & 3) << 4;   // fragment-read swizzle (byte)

    stage(kst);

    for (int k0 = kst; k0 < K; k0 += BK) {
        __syncthreads();   // staged tile visible (vmcnt drain + barrier)

        bf16x8 fah[4], fal[4], fbh[4], fbl[4];
        #pragma unroll
        for (int i = 0; i < 4; ++i) {
            const int r = wr * 64 + i * 16 + fr;
            const int cb = r * 64 + ((fkb * 16) ^ swzf);
            fah[i] = *(const bf16x8*)((const char*)lds + cb);
            fal[i] = *(const bf16x8*)((const char*)lds + 8192 + cb);
        }
        #pragma unroll
        for (int j = 0; j < 4; ++j) {
            const int c = wc * 64 + j * 16 + fr;
            const int cb = c * 64 + ((fkb * 16) ^ swzf);
            fbh[j] = *(const bf16x8*)((const char*)lds + 16384 + cb);
            fbl[j] = *(const bf16x8*)((const char*)lds + 24576 + cb);
        }
        __syncthreads();   // all reads done -> LDS reusable

        if (k0 + BK < K) stage(k0 + BK);   // loads fly during MFMA

        #pragma unroll
        for (int i = 0; i < 4; ++i)
            #pragma unroll
            for (int j = 0; j < 4; ++j) {
                acc[i][j] = __builtin_amdgcn_mfma_f32_16x16x32_bf16(fah[i], fbh[j], acc[i][j], 0, 0, 0);
                acc[i][j] = __builtin_amdgcn_mfma_f32_16x16x32_bf16(fah[i], fbl[j], acc[i][j], 0, 0, 0);
                acc[i][j] = __builtin_amdgcn_mfma_f32_16x16x32_bf16(fal[i], fbh[j], acc[i][j], 0, 0, 0);
            }
    }

    const int crow0 = (lane >> 4) * 4;
    #pragma unroll
    for (int i = 0; i < 4; ++i) {
        #pragma unroll
        for (int j = 0; j < 4; ++j) {
            #pragma unroll
            for (int r = 0; r < 4; ++r) {
                const int gm = m0 + wr * 64 + i * 16 + crow0 + r;
                const int gn = n0 + wc * 64 + j * 16 + fr;
                if (gm < M && gn < N) {
                    const long idx = cOff + (long)gm * ldc + gn;
                    float v = acc[i][j][r] * alpha;
                    if (addf) v += addf[idx];
                    if (addh) v += (float)addh[idx] + (float)addl[idx];
                    if (bias) v += bias[gn];
                    if (relu) v = fmaxf(v, 0.f);
                    if (Cf) Cf[idx] = v;
                    if (Chi) { __bf16 h, l; cvt_hl(v, h, l); Chi[idx] = h; Clo[idx] = l; }
                }
            }
        }
    }
}

// ============== transposes ==============
__global__ __launch_bounds__(256)
void t2hl(const __bf16* __restrict__ ih, const __bf16* __restrict__ il,
          __bf16* __restrict__ oh, __bf16* __restrict__ ol,
          int R, int C, long siZ, long soZ)
{
    __shared__ __bf16 th[32][34], tl[32][34];
    const int z = blockIdx.z;
    const long iB = (long)z * siZ, oB = (long)z * soZ;
    const int c0 = blockIdx.x * 32, r0 = blockIdx.y * 32;
    const int tx = threadIdx.x & 31, tg = threadIdx.x >> 5;
    #pragma unroll
    for (int rr = tg; rr < 32; rr += 8) {
        const int r = r0 + rr, c = c0 + tx;
        const bool ok = (r < R && c < C);
        const long idx = iB + (long)r * C + c;
        th[rr][tx] = ok ? ih[idx] : (__bf16)0.f;
        tl[rr][tx] = ok ? il[idx] : (__bf16)0.f;
    }
    __syncthreads();
    #pragma unroll
    for (int cc = tg; cc < 32; cc += 8) {
        const int c = c0 + cc, r = r0 + tx;
        if (c < C && r < R) {
            const long idx = oB + (long)c * R + r;
            oh[idx] = th[tx][cc]; ol[idx] = tl[tx][cc];
        }
    }
}

__global__ __launch_bounds__(256)
void rot3d_hl(const __bf16* __restrict__ ih, const __bf16* __restrict__ il,
              __bf16* __restrict__ oh, __bf16* __restrict__ ol,
              int Ad, int Bd, int Cd, long sIn, long sOut)
{
    __shared__ __bf16 th[32][34], tl[32][34];
    const int zz = blockIdx.z;
    const int b = zz % Bd, bat = zz / Bd;
    const long iB = (long)bat * sIn, oB = (long)bat * sOut;
    const int c0 = blockIdx.x * 32, a0 = blockIdx.y * 32;
    const int tx = threadIdx.x & 31, tg = threadIdx.x >> 5;
    #pragma unroll
    for (int aa = tg; aa < 32; aa += 8) {
        const int a = a0 + aa, c = c0 + tx;
        const bool ok = (a < Ad && c < Cd);
        const long idx = iB + ((long)a * Bd + b) * Cd + c;
        th[aa][tx] = ok ? ih[idx] : (__bf16)0.f;
        tl[aa][tx] = ok ? il[idx] : (__bf16)0.f;
    }
    __syncthreads();
    #pragma unroll
    for (int cc = tg; cc < 32; cc += 8) {
        const int c = c0 + cc, a = a0 + tx;
        if (c < Cd && a < Ad) {
            const long idx = oB + ((long)c * Bd + b) * Ad + a;
            oh[idx] = th[tx][cc]; ol[idx] = tl[tx][cc];
        }
    }
}

// f32 [R][C] -> transposed hi/lo [C][Rd] (rows R..Rd zero)
__global__ __launch_bounds__(256)
void t2cvtp(const float* __restrict__ in, __bf16* __restrict__ oh, __bf16* __restrict__ ol,
            int R, int C, int Rd)
{
    __shared__ float t[32][33];
    const int c0 = blockIdx.x * 32, r0 = blockIdx.y * 32;
    const int tx = threadIdx.x & 31, tg = threadIdx.x >> 5;
    #pragma unroll
    for (int rr = tg; rr < 32; rr += 8) {
        const int r = r0 + rr, c = c0 + tx;
        t[rr][tx] = (r < R && c < C) ? in[(long)r * C + c] : 0.f;
    }
    __syncthreads();
    #pragma unroll
    for (int cc = tg; cc < 32; cc += 8) {
        const int c = c0 + cc, r = r0 + tx;
        if (c < C && r < Rd) {
            __bf16 h, l; cvt_hl(t[tx][cc], h, l);
            oh[(long)c * Rd + r] = h; ol[(long)c * Rd + r] = l;
        }
    }
}

__global__ __launch_bounds__(256)
void transpose2d(const float* __restrict__ in, float* __restrict__ out, int R, int C)
{
    __shared__ float t[32][33];
    const int c0 = blockIdx.x * 32, r0 = blockIdx.y * 32;
    const int tx = threadIdx.x & 31, tg = threadIdx.x >> 5;
    #pragma unroll
    for (int rr = tg; rr < 32; rr += 8) {
        const int r = r0 + rr, c = c0 + tx;
        t[rr][tx] = (r < R && c < C) ? in[(long)r * C + c] : 0.f;
    }
    __syncthreads();
    #pragma unroll
    for (int cc = tg; cc < 32; cc += 8) {
        const int c = c0 + cc, r = r0 + tx;
        if (c < C && r < R) out[(long)c * R + r] = t[tx][cc];
    }
}

// f32 weights [Rsrc][Ks] (row stride sld) -> hi/lo [Rdst][Kd], zero-padded rows/cols
__global__ __launch_bounds__(256)
void cvtp(const float* __restrict__ src, __bf16* __restrict__ oh, __bf16* __restrict__ ol,
          int Rsrc, int Rdst, int Ks, int Kd, int sld)
{
    const long i = (long)blockIdx.x * 256 + threadIdx.x;
    if (i >= (long)Rdst * Kd) return;
    const int r = (int)(i / Kd), k = (int)(i % Kd);
    const float v = (r < Rsrc && k < Ks) ? src[(long)r * sld + k] : 0.f;
    __bf16 h, l; cvt_hl(v, h, l);
    oh[i] = h; ol[i] = l;
}

// ============== table builders ==============
__global__ __launch_bounds__(256)
void make_dft_hl(__bf16* WfH, __bf16* WfL, __bf16* WiH, __bf16* WiL)
{
    const int i = blockIdx.x * 256 + threadIdx.x;
    const double w0 = 2.0 * 3.14159265358979323846 / 256.0;
    {
        const int n = i & 255, r = i >> 8, m = r & 127;
        const double th = (double)((m * n) & 255) * w0;
        const float v = (r < 128) ? (float)cos(th) : (float)-sin(th);
        __bf16 h, l; cvt_hl(v, h, l); WfH[i] = h; WfL[i] = l;
    }
    {
        const int k = i & 255, nn = i >> 8, m = k & 127;
        const double th = (double)((m * nn) & 255) * w0;
        const float sc = (m == 0 ? 1.0f : 2.0f) / 256.0f;
        const float v = (k < 128) ? sc * (float)cos(th) : -sc * (float)sin(th);
        __bf16 h, l; cvt_hl(v, h, l); WiH[i] = h; WiL[i] = l;
    }
}

__global__ __launch_bounds__(256)
void make_P1_hl(const float* __restrict__ pct, const float* __restrict__ wq,
                __bf16* __restrict__ PH, __bf16* __restrict__ PL)
{
    const long i = (long)blockIdx.x * 256 + threadIdx.x;
    const int y = (int)(i & 127);
    const int l = (int)((i >> 7) & 127);
    const int m = (int)(i >> 14);
    const float v = pct[((long)l * MM + m) * NLAT + y] * wq[y];
    __bf16 h, lo; cvt_hl(v, h, lo); PH[i] = h; PL[i] = lo;
}

__global__ __launch_bounds__(256)
void make_Q_hl(const float* __restrict__ pct, __bf16* __restrict__ QH, __bf16* __restrict__ QL)
{
    __shared__ float t[32][33];
    const int m = blockIdx.z;
    const int y0 = blockIdx.x * 32, l0 = blockIdx.y * 32;
    const int tx = threadIdx.x & 31, tg = threadIdx.x >> 5;
    #pragma unroll
    for (int ll = tg; ll < 32; ll += 8)
        t[ll][tx] = pct[((long)(l0 + ll) * MM + m) * NLAT + (y0 + tx)];
    __syncthreads();
    #pragma unroll
    for (int yy = tg; yy < 32; yy += 8) {
        const long idx = ((long)m * NLAT + (y0 + yy)) * MM + (l0 + tx);
        __bf16 h, l; cvt_hl(t[tx][yy], h, l);
        QH[idx] = h; QL[idx] = l;
    }
}

// ============== host ==============
struct HL { __bf16 *h, *l; };

extern "C" void kernel_launch(void* const* d_in, const int* in_sizes, int n_in,
                              void* d_out, int out_size, void* d_ws, size_t ws_size,
                              hipStream_t stream)
{
    const float* x       = (const float*)d_in[0];
    const float* pct     = (const float*)d_in[1];
    const float* wq      = (const float*)d_in[2];
    const float* pos     = (const float*)d_in[3];
    const float* enc_w   = (const float*)d_in[4];
    const float* spec_re = (const float*)d_in[5];
    const float* spec_im = (const float*)d_in[6];
    const float* skip_w  = (const float*)d_in[7];
    const float* skip_b  = (const float*)d_in[8];
    const float* mlp_w1  = (const float*)d_in[9];
    const float* mlp_b1  = (const float*)d_in[10];
    const float* mlp_w2  = (const float*)d_in[11];
    const float* mlp_b2  = (const float*)d_in[12];
    const float* dec_w1  = (const float*)d_in[13];
    const float* dec_b1  = (const float*)d_in[14];
    const float* dec_w2  = (const float*)d_in[15];

    char* base = (char*)d_ws;
    size_t off = 0;
    auto alloc = [&](size_t bytes) -> char* {
        char* p = base + off; off += (bytes + 255) & ~(size_t)255; return p;
    };
    auto allocHL = [&](long elems) -> HL {
        HL r; r.h = (__bf16*)alloc((size_t)elems * 2); r.l = (__bf16*)alloc((size_t)elems * 2); return r;
    };

    HL Wf  = allocHL(65536);
    HL Wi2 = allocHL(65536);
    HL P1  = allocHL(2097152);
    HL Q   = allocHL(2097152);
    HL enc = allocHL(256 * 64);
    HL skp = allocHL(4 * 65536);
    HL w1  = allocHL(4 * 131072);
    HL w2  = allocHL(4 * 131072);
    HL d1h = allocHL(512 * 256);
    HL d1x = allocHL(512 * 64);
    HL d2  = allocHL(128 * 512);
    HL xT  = allocHL((long)YN * 64);
    float* posT = (float*)alloc((size_t)8388608 * 4);
    HL hA  = allocHL(8388608);
    HL hB  = allocHL(8388608);
    HL S1  = allocHL(8388608);
    HL S2  = allocHL(8388608);
    HL mb  = allocHL(16777216);
    HL WtR = allocHL(8388608);
    HL WtI = allocHL(8388608);
    float* U = (float*)alloc((size_t)8388608 * 4);
    float* D = (float*)alloc((size_t)16777216 * 4);
    if (off > ws_size) return;

    // ---- tables & weight conversion ----
    make_dft_hl<<<256, 256, 0, stream>>>(Wf.h, Wf.l, Wi2.h, Wi2.l);
    make_P1_hl<<<8192, 256, 0, stream>>>(pct, wq, P1.h, P1.l);
    make_Q_hl<<<dim3(4, 4, 128), 256, 0, stream>>>(pct, Q.h, Q.l);
    cvtp<<<(256 * 64 + 255) / 256, 256, 0, stream>>>(enc_w, enc.h, enc.l, 256, 256, 36, 64, 36);
    cvtp<<<(1024 * 256 + 255) / 256, 256, 0, stream>>>(skip_w, skp.h, skp.l, 1024, 1024, 256, 256, 256);
    cvtp<<<(2048 * 256 + 255) / 256, 256, 0, stream>>>(mlp_w1, w1.h, w1.l, 2048, 2048, 256, 256, 256);
    cvtp<<<(1024 * 512 + 255) / 256, 256, 0, stream>>>(mlp_w2, w2.h, w2.l, 1024, 1024, 512, 512, 512);
    cvtp<<<(512 * 256 + 255) / 256, 256, 0, stream>>>(dec_w1, d1h.h, d1h.l, 512, 512, 256, 256, 292);
    cvtp<<<(512 * 64 + 255) / 256, 256, 0, stream>>>(dec_w1 + 256, d1x.h, d1x.l, 512, 512, 36, 64, 292);
    cvtp<<<(128 * 512 + 255) / 256, 256, 0, stream>>>(dec_w2, d2.h, d2.l, 6, 128, 512, 512, 512);
    t2cvtp<<<dim3(1024, 2), 256, 0, stream>>>(x, xT.h, xT.l, 36, YN, 64);
    transpose2d<<<dim3(1024, 8), 256, 0, stream>>>(pos, posT, 256, YN);

    auto g = [&](HL A, HL B, int M, int N, int K, int lda, int ldb, int ldc,
                 long sAz, long sBz, unsigned zm, long sCz, int Z,
                 float* Cf, HL Co, const float* addf, HL ad, const float* bias,
                 int kfz, float alpha, int relu, long Aoff = 0, long Boff = 0, long Coff = 0) {
        dim3 grid((N + BN - 1) / BN, (M + BM - 1) / BM, Z);
        gemm_hl<<<grid, 256, 0, stream>>>(
            A.h + Aoff, A.l + Aoff, B.h + Boff, B.l + Boff, M, N, K, lda, ldb, ldc,
            sAz, sBz, zm, sCz, Cf,
            Co.h ? Co.h + Coff : nullptr, Co.l ? Co.l + Coff : nullptr,
            addf, ad.h, ad.l, bias, kfz, alpha, relu);
    };
    const HL NIL = {nullptr, nullptr};

    // ---- encoder ----
    g(xT, enc, YN, EMB, 64, 64, 64, EMB, 0, 0, 0u, 0, 1,
      nullptr, hA, posT, NIL, nullptr, 0, 1.0f, 0);

    HL hcur = hA, hnext = hB;

    for (int l = 0; l < NLAYERS; ++l) {
        t2hl<<<dim3(8, 1024, 1), 256, 0, stream>>>(hcur.h, hcur.l, S1.h, S1.l, YN, 256, 0, 0);
        g(Wf, S1, 256, YN, 256, 256, 256, YN, 0, 0, 0u, 0, 1,
          nullptr, S2, nullptr, NIL, nullptr, 0, 1.0f, 0);
        g(S2, P1, 256, 128, 128, 128, 128, 128, 32768, 16384, 127u, 32768, 256,
          nullptr, S1, nullptr, NIL, nullptr, 0, 1.0f, 0);
        t2hl<<<dim3(4, 1024, 2), 256, 0, stream>>>(S1.h, S1.l, S2.h, S2.l, 32768, 128, RB, RB);
        t2cvtp<<<dim3(4, 2048), 256, 0, stream>>>(spec_re + (long)l * 8388608, WtR.h, WtR.l, 65536, 128, 65536);
        t2cvtp<<<dim3(4, 2048), 256, 0, stream>>>(spec_im + (long)l * 8388608, WtI.h, WtI.l, 65536, 128, 65536);
        g(WtR, S2, 256, 128, 256, 256, 256, 128, 65536, 32768, 0xFFFFFFFFu, 32768, 128,
          nullptr, S1, nullptr, NIL, nullptr, 0, 1.0f, 0);
        g(WtR, S2, 256, 128, 256, 256, 256, 128, 65536, 32768, 0xFFFFFFFFu, 32768, 128,
          nullptr, S1, nullptr, NIL, nullptr, 0, 1.0f, 0, 0, RB, RB);
        g(WtI, S2, 256, 128, 256, 256, 256, 128, 65536, 32768, 0xFFFFFFFFu, 32768, 128,
          nullptr, S1, nullptr, S1, nullptr, 0, -1.0f, 0, 0, RB, 0);
        g(WtI, S2, 256, 128, 256, 256, 256, 128, 65536, 32768, 0xFFFFFFFFu, 32768, 128,
          nullptr, {S1.h + RB, S1.l + RB}, nullptr, {S1.h + RB, S1.l + RB}, nullptr, 0, 1.0f, 0, 0, 0, 0);
        rot3d_hl<<<dim3(4, 4, 512), 256, 0, stream>>>(S1.h, S1.l, S2.h, S2.l, 128, 256, 128, RB, RB);
        g(S2, Q, 256, 128, 128, 128, 128, 128, 32768, 16384, 127u, 32768, 256,
          nullptr, S1, nullptr, NIL, nullptr, 1, 1.0f, 0);
        t2hl<<<dim3(1024, 8, 1), 256, 0, stream>>>(S1.h, S1.l, S2.h, S2.l, 256, YN, 0, 0);
        g(Wi2, S2, 256, 256, 256, 256, 32768, 256, 0, 256, 0xFFFFFFFFu, 65536, 128,
          U, NIL, nullptr, NIL, nullptr, 0, 1.0f, 0);
        g(hcur, skp, YN, EMB, 256, 256, 256, EMB, 0, 0, 0u, 0, 1,
          nullptr, S1, U, NIL, skip_b + (long)l * EMB, 0, 1.0f, 0, 0, (long)l * 65536, 0);
        g(S1, w1, YN, HID, 256, 256, 256, HID, 0, 0, 0u, 0, 1,
          nullptr, mb, nullptr, NIL, mlp_b1 + (long)l * HID, 0, 1.0f, 1, 0, (long)l * 131072, 0);
        g(mb, w2, YN, EMB, 512, 512, 512, EMB, 0, 0, 0u, 0, 1,
          nullptr, hnext, nullptr, hcur, mlp_b2 + (long)l * EMB, 0, 1.0f, 0, 0, (long)l * 131072, 0);
        HL t = hcur; hcur = hnext; hnext = t;
    }

    // ---- decoder ----
    g(hcur, d1h, YN, HID, 256, 256, 256, HID, 0, 0, 0u, 0, 1,
      D, NIL, nullptr, NIL, nullptr, 0, 1.0f, 0);
    g(xT, d1x, YN, HID, 64, 64, 64, HID, 0, 0, 0u, 0, 1,
      nullptr, mb, D, NIL, dec_b1, 0, 1.0f, 1);
    g(mb, d2, YN, OUTCH, 512, 512, 512, OUTCH, 0, 0, 0u, 0, 1,
      U, NIL, nullptr, NIL, nullptr, 0, 1.0f, 0);
    transpose2d<<<dim3(1, 1024), 256, 0, stream>>>(U, (float*)d_out, YN, OUTCH);

    (void)in_sizes; (void)n_in; (void)out_size;
}